// Round 5
// baseline (137.515 us; speedup 1.0000x reference)
//
#include <hip/hip_runtime.h>

// GCN aggregator: out[r,:] = relu( (1/25 * sum_s F[idx[r,s],:]) @ W )
// r in [0, 32768), D_IN = D_OUT = 128, S = 25.
//
// Round 5: same two-phase structure (G = bf16(F @ W) via MFMA, then
// out = relu(mean_s G[idx])), plus:
//  - G stored with __builtin_nontemporal_store: no-allocate => gather reads
//    clean L3 lines instead of dirty cross-XCD L2 lines (fabric slow path).
//  - A loads nontemporal (streamed once, don't pollute L2).
//  - out stores nontemporal (written once, never re-read; keeps L2 for G).
//  - gather restructured: 1 row-chunk/thread, accumulate-on-arrival (kills the
//    100-VGPR v[25] array of R3/R4), __launch_bounds__(256,8) => 32 waves/CU.

#define DEG 25
#define DIM 128

typedef __attribute__((ext_vector_type(8))) short short8;    // 8 bf16 = 4 VGPR
typedef __attribute__((ext_vector_type(4))) float floatx4;   // MFMA acc
typedef __attribute__((ext_vector_type(4))) unsigned uintx4;

__device__ __forceinline__ unsigned short f2bf(float f) {
    // round-to-nearest-even fp32 -> bf16 (inputs finite)
    unsigned u = __float_as_uint(f);
    return (unsigned short)((u + 0x7fffu + ((u >> 16) & 1u)) >> 16);
}

__device__ __forceinline__ float4 ldnt_f4(const float* p) {
    uintx4 u = __builtin_nontemporal_load((const uintx4*)p);
    return __builtin_bit_cast(float4, u);
}

// ---------------------------------------------------------------- GEMM ------
// G[M,128] = bf16( A[M,128] @ B[128,128] ), 128-row blocks, 4 waves,
// each wave: 32 rows x 128 cols via 16x16x32 bf16 MFMA.
// G rows use the PERMUTED layout: row position p = l16*8 + nt holds col
// 16*nt + l16, so each lane's 8 C-frag values are 16 B contiguous.
#define BSTRIDE 136

__global__ __launch_bounds__(256, 2) void gemm_fw(
    const float* __restrict__ A,       // [M,128] fp32
    const float* __restrict__ B,       // [128,128] fp32
    unsigned short* __restrict__ G,    // [M,128] bf16, permuted rows
    int M)
{
    __shared__ unsigned short sBt[DIM * BSTRIDE];  // B^T [n][k], 34.8 KB

    const int tid = threadIdx.x;

    // ---- stage B transposed with fp32->bf16 (once per block)
    {
        const float4* B4 = (const float4*)B;
#pragma unroll
        for (int i = 0; i < 16; ++i) {
            const int linear = i * 256 + tid;   // 0..4095 float4s
            const int k  = linear >> 5;         // B row
            const int c4 = linear & 31;         // float4 within row
            const float4 v = B4[linear];
            const int n = c4 * 4;
            sBt[(n + 0) * BSTRIDE + k] = f2bf(v.x);
            sBt[(n + 1) * BSTRIDE + k] = f2bf(v.y);
            sBt[(n + 2) * BSTRIDE + k] = f2bf(v.z);
            sBt[(n + 3) * BSTRIDE + k] = f2bf(v.w);
        }
    }
    __syncthreads();

    const int wave = tid >> 6;
    const int lane = tid & 63;
    const int quad = lane >> 4;    // 0..3
    const int l16  = lane & 15;

    const int rw0 = blockIdx.x * 128 + wave * 32;   // wave's first row

    floatx4 acc[2][8];
#pragma unroll
    for (int mt = 0; mt < 2; ++mt)
#pragma unroll
        for (int nt = 0; nt < 8; ++nt)
            acc[mt][nt] = (floatx4){0.f, 0.f, 0.f, 0.f};

#pragma unroll
    for (int kt = 0; kt < 4; ++kt) {
        const int k0 = kt * 32;

        // A-frags: lane holds A[m=l16][k=k0+quad*8+j], j=0..7 (coalesced,
        // streamed once -> nontemporal).
        short8 afrag[2];
#pragma unroll
        for (int mt = 0; mt < 2; ++mt) {
            int row = rw0 + mt * 16 + l16;
            if (row >= M) row = M - 1;          // tail clamp (stores guarded)
            const float* ap = A + (size_t)row * DIM + k0 + quad * 8;
            const float4 x = ldnt_f4(ap);
            const float4 y = ldnt_f4(ap + 4);
            unsigned p0 = (unsigned)f2bf(x.x) | ((unsigned)f2bf(x.y) << 16);
            unsigned p1 = (unsigned)f2bf(x.z) | ((unsigned)f2bf(x.w) << 16);
            unsigned p2 = (unsigned)f2bf(y.x) | ((unsigned)f2bf(y.y) << 16);
            unsigned p3 = (unsigned)f2bf(y.z) | ((unsigned)f2bf(y.w) << 16);
            uintx4 packed = (uintx4){p0, p1, p2, p3};
            afrag[mt] = __builtin_bit_cast(short8, packed);
        }

        // B-frags from LDS: lane holds B[k=k0+quad*8+j][n=nt*16+l16]
#pragma unroll
        for (int nt = 0; nt < 8; ++nt) {
            const uintx4 u = *(const uintx4*)&sBt[(nt * 16 + l16) * BSTRIDE + k0 + quad * 8];
            const short8 bfrag = __builtin_bit_cast(short8, u);
#pragma unroll
            for (int mt = 0; mt < 2; ++mt)
                acc[mt][nt] = __builtin_amdgcn_mfma_f32_16x16x32_bf16(
                    afrag[mt], bfrag, acc[mt][nt], 0, 0, 0);
        }
    }

    // ---- permuted store, nontemporal dwordx4 (no-allocate: gather will read
    // clean L3 lines, not dirty cross-XCD L2 lines).
    uintx4* G4 = (uintx4*)G;
#pragma unroll
    for (int mt = 0; mt < 2; ++mt)
#pragma unroll
        for (int r = 0; r < 4; ++r) {
            const int row = rw0 + mt * 16 + quad * 4 + r;
            if (row < M) {
                unsigned p0 = (unsigned)f2bf(acc[mt][0][r]) | ((unsigned)f2bf(acc[mt][1][r]) << 16);
                unsigned p1 = (unsigned)f2bf(acc[mt][2][r]) | ((unsigned)f2bf(acc[mt][3][r]) << 16);
                unsigned p2 = (unsigned)f2bf(acc[mt][4][r]) | ((unsigned)f2bf(acc[mt][5][r]) << 16);
                unsigned p3 = (unsigned)f2bf(acc[mt][6][r]) | ((unsigned)f2bf(acc[mt][7][r]) << 16);
                __builtin_nontemporal_store((uintx4){p0, p1, p2, p3},
                                            &G4[(size_t)row * 16 + l16]);
            }
        }
}

// ------------------------------------------------------- gather-mean-relu ---
// out[r,:] = relu( 1/25 * sum_s G[idx[r,s],:] ), G rows 256 B bf16 (permuted).
// One row-chunk per thread: grp = row slot (16/block), l16 = 16 B chunk.
// Accumulate on arrival: no 25-wide live array, scheduler picks the MLP
// window under the 64-VGPR cap (8 waves/EU = 32 waves/CU).
#define GRPB 16

__global__ __launch_bounds__(256, 8) void gather_mean_relu(
    const unsigned short* __restrict__ G,   // [n_nodes,128] bf16 permuted
    const int* __restrict__ idx,            // [n_rows,25]
    float* __restrict__ out,                // [n_rows,128] fp32
    int n_rows)
{
    __shared__ int sIdx[GRPB * DEG];

    const int tid  = threadIdx.x;
    const int row0 = blockIdx.x * GRPB;

    for (int i = tid; i < GRPB * DEG; i += 256)
        sIdx[i] = idx[(size_t)row0 * DEG + i];
    __syncthreads();

    const int grp = tid >> 4;   // 0..15: row slot
    const int l16 = tid & 15;   // 16 B chunk of the 256 B row
    const uint4* G4 = (const uint4*)G;      // 16 uint4 per row
    const int* ip = &sIdx[grp * DEG];

    float a0 = 0.f, a1 = 0.f, a2 = 0.f, a3 = 0.f;
    float a4 = 0.f, a5 = 0.f, a6 = 0.f, a7 = 0.f;
#pragma unroll
    for (int s = 0; s < DEG; ++s) {
        const uint4 v = G4[(size_t)ip[s] * 16 + l16];
        a0 += __uint_as_float(v.x << 16);
        a1 += __uint_as_float(v.x & 0xffff0000u);
        a2 += __uint_as_float(v.y << 16);
        a3 += __uint_as_float(v.y & 0xffff0000u);
        a4 += __uint_as_float(v.z << 16);
        a5 += __uint_as_float(v.z & 0xffff0000u);
        a6 += __uint_as_float(v.w << 16);
        a7 += __uint_as_float(v.w & 0xffff0000u);
    }
    const float inv = 1.0f / 25.0f;
    // chunk l16 holds cols {16j + l16}; for fixed j the 16 group-lanes cover
    // 16 consecutive fp32 => contiguous 64 B runs. NT: out is never re-read.
    float* orow = out + (size_t)(row0 + grp) * DIM + l16;
    __builtin_nontemporal_store(fmaxf(a0 * inv, 0.f), orow);
    __builtin_nontemporal_store(fmaxf(a1 * inv, 0.f), orow + 16);
    __builtin_nontemporal_store(fmaxf(a2 * inv, 0.f), orow + 32);
    __builtin_nontemporal_store(fmaxf(a3 * inv, 0.f), orow + 48);
    __builtin_nontemporal_store(fmaxf(a4 * inv, 0.f), orow + 64);
    __builtin_nontemporal_store(fmaxf(a5 * inv, 0.f), orow + 80);
    __builtin_nontemporal_store(fmaxf(a6 * inv, 0.f), orow + 96);
    __builtin_nontemporal_store(fmaxf(a7 * inv, 0.f), orow + 112);
}

// --------------------------------------------- fallback (round-2 kernel) ----
#define RPB 16
#define CG 32

__device__ __forceinline__ float4 relu4(float4 v) {
    return make_float4(fmaxf(v.x, 0.f), fmaxf(v.y, 0.f),
                       fmaxf(v.z, 0.f), fmaxf(v.w, 0.f));
}

__global__ __launch_bounds__(256, 4) void gcn_fused(
    const float* __restrict__ F, const int* __restrict__ idx,
    const float* __restrict__ W, float* __restrict__ out, int n_rows)
{
    __shared__ float4 sV[RPB * CG];
    __shared__ int    sIdx[RPB * DEG];

    const float4* F4 = (const float4*)F;
    const float4* W4 = (const float4*)W;
    float4* out4 = (float4*)out;

    const int tid = threadIdx.x;
    const int row0 = blockIdx.x * RPB;

    for (int i = tid; i < RPB * DEG; i += 256)
        sIdx[i] = idx[(size_t)row0 * DEG + i];
    __syncthreads();

    const int cg = tid & 31;
    const int rs = tid >> 5;

#pragma unroll
    for (int rr = 0; rr < 2; ++rr) {
        const int r = rs + rr * 8;
        int j[DEG];
#pragma unroll
        for (int s = 0; s < DEG; ++s) j[s] = sIdx[r * DEG + s];
        float4 acc = make_float4(0.f, 0.f, 0.f, 0.f);
#pragma unroll
        for (int s = 0; s < DEG; ++s) {
            float4 f = F4[(size_t)j[s] * CG + cg];
            acc.x += f.x; acc.y += f.y; acc.z += f.z; acc.w += f.w;
        }
        const float inv = 1.0f / 25.0f;
        acc.x *= inv; acc.y *= inv; acc.z *= inv; acc.w *= inv;
        sV[r * CG + cg] = acc;
    }
    __syncthreads();

    const float4* vA = &sV[rs * CG];
    const float4* vB = &sV[(rs + 8) * CG];
    float4 o0 = make_float4(0.f, 0.f, 0.f, 0.f);
    float4 o1 = make_float4(0.f, 0.f, 0.f, 0.f);
#pragma unroll 4
    for (int d4 = 0; d4 < CG; ++d4) {
        const float4 a = vA[d4];
        const float4 b = vB[d4];
        const float4 w0 = W4[(size_t)(4 * d4 + 0) * CG + cg];
        const float4 w1 = W4[(size_t)(4 * d4 + 1) * CG + cg];
        const float4 w2 = W4[(size_t)(4 * d4 + 2) * CG + cg];
        const float4 w3 = W4[(size_t)(4 * d4 + 3) * CG + cg];
        o0.x += a.x*w0.x + a.y*w1.x + a.z*w2.x + a.w*w3.x;
        o0.y += a.x*w0.y + a.y*w1.y + a.z*w2.y + a.w*w3.y;
        o0.z += a.x*w0.z + a.y*w1.z + a.z*w2.z + a.w*w3.z;
        o0.w += a.x*w0.w + a.y*w1.w + a.z*w2.w + a.w*w3.w;
        o1.x += b.x*w0.x + b.y*w1.x + b.z*w2.x + b.w*w3.x;
        o1.y += b.x*w0.y + b.y*w1.y + b.z*w2.y + b.w*w3.y;
        o1.z += b.x*w0.z + b.y*w1.z + b.z*w2.z + b.w*w3.z;
        o1.w += b.x*w0.w + b.y*w1.w + b.z*w2.w + b.w*w3.w;
    }
    out4[(size_t)(row0 + rs) * CG + cg]     = relu4(o0);
    out4[(size_t)(row0 + rs + 8) * CG + cg] = relu4(o1);
}

// ----------------------------------------------------------------------------
extern "C" void kernel_launch(void* const* d_in, const int* in_sizes, int n_in,
                              void* d_out, int out_size, void* d_ws, size_t ws_size,
                              hipStream_t stream) {
    const float* F   = (const float*)d_in[0];   // features [100000,128] fp32
    const int*   idx = (const int*)d_in[1];     // sample_res [8,4096,25] int32
    const float* W   = (const float*)d_in[2];   // weights [128,128] fp32
    float* out = (float*)d_out;                 // [8,4096,128] fp32

    const int n_nodes = in_sizes[0] / DIM;      // 100000
    const int n_rows  = in_sizes[1] / DEG;      // 32768

    const size_t need = (size_t)n_nodes * DIM * sizeof(unsigned short);
    if (ws_size >= need) {
        unsigned short* G = (unsigned short*)d_ws;
        gemm_fw<<<(n_nodes + 127) / 128, 256, 0, stream>>>(F, W, G, n_nodes);
        gather_mean_relu<<<n_rows / GRPB, 256, 0, stream>>>(G, idx, out, n_rows);
    } else {
        gcn_fused<<<n_rows / RPB, 256, 0, stream>>>(F, idx, W, out, n_rows);
    }
}

// Round 6
// 131.005 us; speedup vs baseline: 1.0497x; 1.0497x over previous
//
#include <hip/hip_runtime.h>

// GCN aggregator: out[r,:] = relu( (1/25 * sum_s F[idx[r,s],:]) @ W )
// r in [0, 32768), D_IN = D_OUT = 128, S = 25.
//
// Round 6 = Round 4 (best, 130.1 us) + NT only on `out` stores.
//  R5 post-mortem: NT on G-store removed producer-XCD dirty-L2 hits (+fabric
//  traffic) and the accumulate-on-arrival gather shrank the outstanding-load
//  window 25 -> ~8; both reverted here.
//  Structure: G = bf16(F @ W) via MFMA (permuted row layout so both the GEMM
//  epilogue and the gather loads are dwordx4), then out = relu(mean_s G[idx]).
//  Gather FETCH ~191 MB matches the random-LRU L2 model (16% hit on a
//  25.6 MB table vs 4 MiB/XCD L2) — structural for bf16.

#define DEG 25
#define DIM 128

typedef __attribute__((ext_vector_type(8))) short short8;    // 8 bf16 = 4 VGPR
typedef __attribute__((ext_vector_type(4))) float floatx4;   // MFMA acc

__device__ __forceinline__ unsigned short f2bf(float f) {
    // round-to-nearest-even fp32 -> bf16 (inputs finite)
    unsigned u = __float_as_uint(f);
    return (unsigned short)((u + 0x7fffu + ((u >> 16) & 1u)) >> 16);
}

// ---------------------------------------------------------------- GEMM ------
// G[M,128] = bf16( A[M,128] @ B[128,128] ), 128-row blocks, 4 waves,
// each wave: 32 rows x 128 cols via 16x16x32 bf16 MFMA.
// G rows use the PERMUTED layout: row position p = l16*8 + nt holds col
// 16*nt + l16, so each lane's 8 C-frag values are 16 B contiguous.
#define BSTRIDE 136

__global__ __launch_bounds__(256, 2) void gemm_fw(
    const float* __restrict__ A,       // [M,128] fp32
    const float* __restrict__ B,       // [128,128] fp32
    unsigned short* __restrict__ G,    // [M,128] bf16, permuted rows
    int M)
{
    __shared__ unsigned short sBt[DIM * BSTRIDE];  // B^T [n][k], 34.8 KB

    const int tid = threadIdx.x;

    // ---- stage B transposed with fp32->bf16 (once per block)
    {
        const float4* B4 = (const float4*)B;
#pragma unroll
        for (int i = 0; i < 16; ++i) {
            const int linear = i * 256 + tid;   // 0..4095 float4s
            const int k  = linear >> 5;         // B row
            const int c4 = linear & 31;         // float4 within row
            const float4 v = B4[linear];
            const int n = c4 * 4;
            sBt[(n + 0) * BSTRIDE + k] = f2bf(v.x);
            sBt[(n + 1) * BSTRIDE + k] = f2bf(v.y);
            sBt[(n + 2) * BSTRIDE + k] = f2bf(v.z);
            sBt[(n + 3) * BSTRIDE + k] = f2bf(v.w);
        }
    }
    __syncthreads();

    const int wave = tid >> 6;
    const int lane = tid & 63;
    const int quad = lane >> 4;    // 0..3
    const int l16  = lane & 15;

    const int rw0 = blockIdx.x * 128 + wave * 32;   // wave's first row

    floatx4 acc[2][8];
#pragma unroll
    for (int mt = 0; mt < 2; ++mt)
#pragma unroll
        for (int nt = 0; nt < 8; ++nt)
            acc[mt][nt] = (floatx4){0.f, 0.f, 0.f, 0.f};

#pragma unroll
    for (int kt = 0; kt < 4; ++kt) {
        const int k0 = kt * 32;

        // A-frags: lane holds A[m=l16][k=k0+quad*8+j], j=0..7 (coalesced).
        short8 afrag[2];
#pragma unroll
        for (int mt = 0; mt < 2; ++mt) {
            int row = rw0 + mt * 16 + l16;
            if (row >= M) row = M - 1;          // tail clamp (stores guarded)
            const float* ap = A + (size_t)row * DIM + k0 + quad * 8;
            const float4 x = *(const float4*)ap;
            const float4 y = *(const float4*)(ap + 4);
            unsigned p0 = (unsigned)f2bf(x.x) | ((unsigned)f2bf(x.y) << 16);
            unsigned p1 = (unsigned)f2bf(x.z) | ((unsigned)f2bf(x.w) << 16);
            unsigned p2 = (unsigned)f2bf(y.x) | ((unsigned)f2bf(y.y) << 16);
            unsigned p3 = (unsigned)f2bf(y.z) | ((unsigned)f2bf(y.w) << 16);
            uint4 packed = make_uint4(p0, p1, p2, p3);
            afrag[mt] = __builtin_bit_cast(short8, packed);
        }

        // B-frags from LDS: lane holds B[k=k0+quad*8+j][n=nt*16+l16]
#pragma unroll
        for (int nt = 0; nt < 8; ++nt) {
            const uint4 u = *(const uint4*)&sBt[(nt * 16 + l16) * BSTRIDE + k0 + quad * 8];
            const short8 bfrag = __builtin_bit_cast(short8, u);
#pragma unroll
            for (int mt = 0; mt < 2; ++mt)
                acc[mt][nt] = __builtin_amdgcn_mfma_f32_16x16x32_bf16(
                    afrag[mt], bfrag, acc[mt][nt], 0, 0, 0);
        }
    }

    // ---- permuted store: C/D elem r of lane = (row quad*4+r, col 16nt+l16).
    // Row position p = l16*8+nt => lane's 8 nt-values are 16 B contiguous at
    // byte offset l16*16; one dwordx4 per (mt,r); wave stores 4 rows/inst.
    // Regular cached store: the producer XCD's L2 keeps dirty lines that the
    // gather can hit (R5 showed NT here costs ~7 us).
    uint4* G4 = (uint4*)G;
#pragma unroll
    for (int mt = 0; mt < 2; ++mt)
#pragma unroll
        for (int r = 0; r < 4; ++r) {
            const int row = rw0 + mt * 16 + quad * 4 + r;
            if (row < M) {
                unsigned p0 = (unsigned)f2bf(acc[mt][0][r]) | ((unsigned)f2bf(acc[mt][1][r]) << 16);
                unsigned p1 = (unsigned)f2bf(acc[mt][2][r]) | ((unsigned)f2bf(acc[mt][3][r]) << 16);
                unsigned p2 = (unsigned)f2bf(acc[mt][4][r]) | ((unsigned)f2bf(acc[mt][5][r]) << 16);
                unsigned p3 = (unsigned)f2bf(acc[mt][6][r]) | ((unsigned)f2bf(acc[mt][7][r]) << 16);
                G4[(size_t)row * 16 + l16] = make_uint4(p0, p1, p2, p3);
            }
        }
}

// ------------------------------------------------------- gather-mean-relu ---
// out[r,:] = relu( 1/25 * sum_s G[idx[r,s],:] ), G rows 256 B bf16 (permuted).
// R4 structure: 16-lane group per row, v[25] array = 25 outstanding 1 KB
// wave-loads (deep MLP window; R5's narrow window regressed).
#define GRPB 32

__global__ __launch_bounds__(256, 4) void gather_mean_relu(
    const unsigned short* __restrict__ G,   // [n_nodes,128] bf16 permuted
    const int* __restrict__ idx,            // [n_rows,25]
    float* __restrict__ out,                // [n_rows,128] fp32
    int n_rows)
{
    __shared__ int sIdx[GRPB * DEG];

    const int tid  = threadIdx.x;
    const int row0 = blockIdx.x * GRPB;

    for (int i = tid; i < GRPB * DEG; i += 256)
        sIdx[i] = idx[(size_t)row0 * DEG + i];
    __syncthreads();

    const int grp = tid >> 4;   // 0..15
    const int l16 = tid & 15;   // which 16 B chunk of the 256 B row
    const uint4* G4 = (const uint4*)G;      // 16 uint4 per row

#pragma unroll
    for (int rr = 0; rr < 2; ++rr) {
        const int r = grp + rr * 16;

        uint4 v[DEG];
#pragma unroll
        for (int s = 0; s < DEG; ++s)
            v[s] = G4[(size_t)sIdx[r * DEG + s] * 16 + l16];

        float a0 = 0.f, a1 = 0.f, a2 = 0.f, a3 = 0.f;
        float a4 = 0.f, a5 = 0.f, a6 = 0.f, a7 = 0.f;
#pragma unroll
        for (int s = 0; s < DEG; ++s) {
            a0 += __uint_as_float(v[s].x << 16);
            a1 += __uint_as_float(v[s].x & 0xffff0000u);
            a2 += __uint_as_float(v[s].y << 16);
            a3 += __uint_as_float(v[s].y & 0xffff0000u);
            a4 += __uint_as_float(v[s].z << 16);
            a5 += __uint_as_float(v[s].z & 0xffff0000u);
            a6 += __uint_as_float(v[s].w << 16);
            a7 += __uint_as_float(v[s].w & 0xffff0000u);
        }
        const float inv = 1.0f / 25.0f;
        // chunk l16 holds cols {16j+l16}; for fixed j the 16 group-lanes cover
        // 16 consecutive fp32 => contiguous 64 B runs. NT: out is never
        // re-read — keep it out of L2 so G stays resident during the gather.
        float* orow = out + (size_t)(row0 + r) * DIM + l16;
        __builtin_nontemporal_store(fmaxf(a0 * inv, 0.f), orow);
        __builtin_nontemporal_store(fmaxf(a1 * inv, 0.f), orow + 16);
        __builtin_nontemporal_store(fmaxf(a2 * inv, 0.f), orow + 32);
        __builtin_nontemporal_store(fmaxf(a3 * inv, 0.f), orow + 48);
        __builtin_nontemporal_store(fmaxf(a4 * inv, 0.f), orow + 64);
        __builtin_nontemporal_store(fmaxf(a5 * inv, 0.f), orow + 80);
        __builtin_nontemporal_store(fmaxf(a6 * inv, 0.f), orow + 96);
        __builtin_nontemporal_store(fmaxf(a7 * inv, 0.f), orow + 112);
    }
}

// --------------------------------------------- fallback (round-2 kernel) ----
#define RPB 16
#define CG 32

__device__ __forceinline__ float4 relu4(float4 v) {
    return make_float4(fmaxf(v.x, 0.f), fmaxf(v.y, 0.f),
                       fmaxf(v.z, 0.f), fmaxf(v.w, 0.f));
}

__global__ __launch_bounds__(256, 4) void gcn_fused(
    const float* __restrict__ F, const int* __restrict__ idx,
    const float* __restrict__ W, float* __restrict__ out, int n_rows)
{
    __shared__ float4 sV[RPB * CG];
    __shared__ int    sIdx[RPB * DEG];

    const float4* F4 = (const float4*)F;
    const float4* W4 = (const float4*)W;
    float4* out4 = (float4*)out;

    const int tid = threadIdx.x;
    const int row0 = blockIdx.x * RPB;

    for (int i = tid; i < RPB * DEG; i += 256)
        sIdx[i] = idx[(size_t)row0 * DEG + i];
    __syncthreads();

    const int cg = tid & 31;
    const int rs = tid >> 5;

#pragma unroll
    for (int rr = 0; rr < 2; ++rr) {
        const int r = rs + rr * 8;
        int j[DEG];
#pragma unroll
        for (int s = 0; s < DEG; ++s) j[s] = sIdx[r * DEG + s];
        float4 acc = make_float4(0.f, 0.f, 0.f, 0.f);
#pragma unroll
        for (int s = 0; s < DEG; ++s) {
            float4 f = F4[(size_t)j[s] * CG + cg];
            acc.x += f.x; acc.y += f.y; acc.z += f.z; acc.w += f.w;
        }
        const float inv = 1.0f / 25.0f;
        acc.x *= inv; acc.y *= inv; acc.z *= inv; acc.w *= inv;
        sV[r * CG + cg] = acc;
    }
    __syncthreads();

    const float4* vA = &sV[rs * CG];
    const float4* vB = &sV[(rs + 8) * CG];
    float4 o0 = make_float4(0.f, 0.f, 0.f, 0.f);
    float4 o1 = make_float4(0.f, 0.f, 0.f, 0.f);
#pragma unroll 4
    for (int d4 = 0; d4 < CG; ++d4) {
        const float4 a = vA[d4];
        const float4 b = vB[d4];
        const float4 w0 = W4[(size_t)(4 * d4 + 0) * CG + cg];
        const float4 w1 = W4[(size_t)(4 * d4 + 1) * CG + cg];
        const float4 w2 = W4[(size_t)(4 * d4 + 2) * CG + cg];
        const float4 w3 = W4[(size_t)(4 * d4 + 3) * CG + cg];
        o0.x += a.x*w0.x + a.y*w1.x + a.z*w2.x + a.w*w3.x;
        o0.y += a.x*w0.y + a.y*w1.y + a.z*w2.y + a.w*w3.y;
        o0.z += a.x*w0.z + a.y*w1.z + a.z*w2.z + a.w*w3.z;
        o0.w += a.x*w0.w + a.y*w1.w + a.z*w2.w + a.w*w3.w;
        o1.x += b.x*w0.x + b.y*w1.x + b.z*w2.x + b.w*w3.x;
        o1.y += b.x*w0.y + b.y*w1.y + b.z*w2.y + b.w*w3.y;
        o1.z += b.x*w0.z + b.y*w1.z + b.z*w2.z + b.w*w3.z;
        o1.w += b.x*w0.w + b.y*w1.w + b.z*w2.w + b.w*w3.w;
    }
    out4[(size_t)(row0 + rs) * CG + cg]     = relu4(o0);
    out4[(size_t)(row0 + rs + 8) * CG + cg] = relu4(o1);
}

// ----------------------------------------------------------------------------
extern "C" void kernel_launch(void* const* d_in, const int* in_sizes, int n_in,
                              void* d_out, int out_size, void* d_ws, size_t ws_size,
                              hipStream_t stream) {
    const float* F   = (const float*)d_in[0];   // features [100000,128] fp32
    const int*   idx = (const int*)d_in[1];     // sample_res [8,4096,25] int32
    const float* W   = (const float*)d_in[2];   // weights [128,128] fp32
    float* out = (float*)d_out;                 // [8,4096,128] fp32

    const int n_nodes = in_sizes[0] / DIM;      // 100000
    const int n_rows  = in_sizes[1] / DEG;      // 32768

    const size_t need = (size_t)n_nodes * DIM * sizeof(unsigned short);
    if (ws_size >= need) {
        unsigned short* G = (unsigned short*)d_ws;
        gemm_fw<<<(n_nodes + 127) / 128, 256, 0, stream>>>(F, W, G, n_nodes);
        gather_mean_relu<<<n_rows / GRPB, 256, 0, stream>>>(G, idx, out, n_rows);
    } else {
        gcn_fused<<<n_rows / RPB, 256, 0, stream>>>(F, idx, W, out, n_rows);
    }
}